// Round 15
// baseline (353.292 us; speedup 1.0000x reference)
//
#include <hip/hip_runtime.h>
#include <stdint.h>

#define CCH 64
#define KK 27
#define WN (KK * CCH * CCH)   // 110592

typedef int v4i __attribute__((ext_vector_type(4)));

// ---------------- prep: weights + affine slice + af rows + requant + zero rows ----
__global__ void __launch_bounds__(256) k_prep(
    const int* __restrict__ x32, const int* __restrict__ mul0p,
    const int* __restrict__ w1_32, const int* __restrict__ w2_32,
    const int* __restrict__ comp1, const int* __restrict__ b1,
    const int* __restrict__ comp2, const int* __restrict__ b2,
    const int* __restrict__ mask,
    int8_t* __restrict__ w1e, int8_t* __restrict__ w2e,
    int* __restrict__ q0, int* __restrict__ q1, int8_t* __restrict__ af,
    int pb1, int af_blocks, int nvox, int total4)
{
    const int bid = blockIdx.x;
    if (bid < pb1) {
        const int gtid = bid * 256 + threadIdx.x;
        if (gtid < WN) {
            w1e[gtid] = (int8_t)w1_32[gtid];
        } else if (gtid < 2 * WN) {
            w2e[gtid - WN] = (int8_t)w2_32[gtid - WN];
        } else if (gtid < 2 * WN + 8192) {
            int u = gtid - 2 * WN;
            const int which = u >> 12;
            u &= 4095;
            const int col = u >> 6, j = u & 63;
            const int* comp = which ? comp2 : comp1;
            const int* bias = which ? b2 : b1;
            int v;
            if (j < 27)       v = comp[j * CCH + col] >> 2;
            else if (j < 54)  v = comp[(j - 27) * CCH + col] & 3;
            else if (j == 54) v = bias[col] >> 6;
            else if (j == 55) v = bias[col] & 63;
            else              v = 0;
            (which ? w2e : w1e)[27 * 4096 + col * 64 + j] = (int8_t)v;
        } else {
            const int u = gtid - 2 * WN - 8192;
            if (u < 16)       q0[(size_t)nvox * 16 + u] = 0;
            else if (u < 32)  q1[(size_t)nvox * 16 + (u - 16)] = 0;
        }
    } else if (bid < pb1 + af_blocks) {
        const int vox = (bid - pb1) * 256 + threadIdx.x;
        if (vox < nvox) {
            int m[27];
#pragma unroll
            for (int k = 0; k < 27; ++k)
                m[k] = mask[(size_t)vox * 27 + k] ? 1 : 0;
            v4i d0, d1, d2, d3;
#pragma unroll
            for (int di = 0; di < 16; ++di) {
                int pk = 0;
#pragma unroll
                for (int b = 0; b < 4; ++b) {
                    const int ch = di * 4 + b;
                    int bv = 0;
                    if (ch < 27)       bv = m[ch] << 2;
                    else if (ch < 54)  bv = m[ch - 27];
                    else if (ch == 54) bv = 64;
                    else if (ch == 55) bv = 1;
                    pk |= bv << (8 * b);
                }
                if (di < 4)       d0[di] = pk;
                else if (di < 8)  d1[di - 4] = pk;
                else if (di < 12) d2[di - 8] = pk;
                else              d3[di - 12] = pk;
            }
            v4i* dst = (v4i*)(af + (size_t)vox * 64);
            dst[0] = d0; dst[1] = d1; dst[2] = d2; dst[3] = d3;
        }
    } else {
        const int i = (bid - pb1 - af_blocks) * 256 + threadIdx.x;
        if (i < total4) {
            const int mul2 = (*mul0p) << 1;
            const int4 v = ((const int4*)x32)[i];
            int r = 0, q;
            q = __mulhi(v.x, mul2); q = q > 127 ? 127 : (q < -127 ? -127 : q); r |= (q & 0xff);
            q = __mulhi(v.y, mul2); q = q > 127 ? 127 : (q < -127 ? -127 : q); r |= (q & 0xff) << 8;
            q = __mulhi(v.z, mul2); q = q > 127 ? 127 : (q < -127 ? -127 : q); r |= (q & 0xff) << 16;
            q = __mulhi(v.w, mul2); q = q > 127 ? 127 : (q < -127 ? -127 : q); r |= (q & 0xff) << 24;
            q0[i] = r;
        }
    }
}

// k-split MFMA conv (r14 structure) + ABLATION template.
// VAR: 0=full 1=no-gather 2=no-mfma 3=no-idx-stream 4=no-barrier 5=no-stores
// REP: internal repeats (diagnostic dispatches use 4 to clear the profiler's
//      ~40us fillBuffer noise floor).
template <int LAYER, int VAR, int REP>
__global__ void __launch_bounds__(256, 2)
k_conv(const int8_t* __restrict__ fin,
       const int* __restrict__ in_idx,
       const int* __restrict__ mask,
       const int8_t* __restrict__ wext,
       const int8_t* __restrict__ af,
       const int* __restrict__ mul1,
       const int* __restrict__ slopep,
       const int* __restrict__ x32,
       int8_t* __restrict__ q1out,
       int* __restrict__ out,
       int nvox, int ntiles)
{
    constexpr bool GATHER_ON = (VAR != 1);
    constexpr bool MFMA_ON   = (VAR != 2);
    constexpr bool PUB_ON    = (VAR != 3);
    constexpr bool BAR_ON    = (VAR != 4);
    constexpr bool STORE_ON  = (VAR != 5);

    __shared__ int s_off[2][16][36];
    __shared__ v4i s_red[2][4][4][64];

    const int tid  = threadIdx.x;
    const int lane = tid & 63;
    const int wv   = tid >> 6;
    const int arow = lane & 15;
    const int srow = lane >> 4;
    const int col  = wv * 16 + arow;

    const int e0 = tid;
    const int e1 = tid + 176;
    const int r0 = e0 / 27, s0 = e0 - r0 * 27;
    const int r1 = e1 / 27, s1 = e1 - r1 * 27;
    const int slot0 = r0 * 36 + (s0 / 7) * 8 + (s0 % 7);
    const int slot1 = r1 * 36 + (s1 / 7) * 8 + (s1 % 7);
    int* const offl = &s_off[0][0][0];
    const int OFFSTR = 16 * 36;

    v4i wreg[7][4];
#pragma unroll
    for (int j = 0; j < 7; ++j)
#pragma unroll
        for (int g = 0; g < 4; ++g)
            wreg[j][g] = *(const v4i*)(wext +
                ((size_t)((7 * wv + j) * CCH + g * 16 + arow)) * CCH + srow * 16);

    const int mul2     = (LAYER == 1) ? (mul1[col] << 1) : 0;
    const int slope128 = (LAYER == 1) ? ((*slopep) << 7) : 0;

    const int stride = gridDim.x;
    const int t0 = blockIdx.x;
    if (t0 >= ntiles) return;
    const int cnt = (ntiles - 1 - t0) / stride + 1;

#define GATHER_A(AN, SN, NB)                                                   \
    {                                                                          \
        if (GATHER_ON) {                                                       \
            const v4i o0_ = *(const v4i*)&s_off[SN][arow][wv * 8];             \
            const v4i o1_ = *(const v4i*)&s_off[SN][arow][wv * 8 + 4];         \
            const int offs_[7] = {o0_[0], o0_[1], o0_[2], o0_[3],              \
                                  o1_[0], o1_[1], o1_[2]};                     \
            _Pragma("unroll")                                                  \
            for (int j = 0; j < 7; ++j) {                                      \
                if (wv == 3 && j == 6) {                                       \
                    AN[6] = *(const v4i*)(af + (size_t)((NB) + arow) * CCH + srow * 16); \
                } else {                                                       \
                    AN[j] = *(const v4i*)(fin + offs_[j] + srow * 16);         \
                }                                                              \
            }                                                                  \
        } else {                                                               \
            _Pragma("unroll")                                                  \
            for (int j = 0; j < 7; ++j) AN[j] = wreg[j][0];                    \
        }                                                                      \
    }

#define EPILOGUE(TOT, NBP, X0, X1, X2, X3)                                     \
    if (LAYER == 1) {                                                          \
        int8_t* rp_ = q1out + (size_t)((NBP) + srow * 4) * CCH + col;          \
        _Pragma("unroll")                                                      \
        for (int r = 0; r < 4; ++r) {                                          \
            const int v_ = TOT[r];                                             \
            const int p_ = (v_ >= 0) ? v_ : __mulhi(v_, slope128);             \
            int q_ = __mulhi(p_, mul2);                                        \
            q_ = q_ > 127 ? 127 : (q_ < -127 ? -127 : q_);                     \
            rp_[r * CCH] = (int8_t)q_;                                         \
        }                                                                      \
    } else {                                                                   \
        int* rp_ = out + (size_t)((NBP) + srow * 4) * CCH + col;               \
        rp_[0 * CCH] = TOT[0] + X0;                                            \
        rp_[1 * CCH] = TOT[1] + X1;                                            \
        rp_[2 * CCH] = TOT[2] + X2;                                            \
        rp_[3 * CCH] = TOT[3] + X3;                                            \
    }

#define ITER(AC, AN, P, DO_EPI, PFCa0, PFCm0, PFCa1, PFCm1,                    \
             PFNa0, PFNm0, PFNa1, PFNm1, XC0, XC1, XC2, XC3, XN0, XN1, XN2, XN3) \
    do {                                                                       \
        if (PUB_ON) {                                                          \
            int tp3_ = t + 3 * stride; if (tp3_ >= ntiles) tp3_ = ntiles - 1;  \
            const size_t b3_ = (size_t)tp3_ * (16 * KK);                       \
            PFNa0 = in_idx[b3_ + e0]; PFNm0 = mask[b3_ + e0];                  \
            PFNa1 = in_idx[b3_ + e1]; PFNm1 = mask[b3_ + e1];                  \
        }                                                                      \
        if (STORE_ON && LAYER == 2) {                                          \
            const int* xp_ = x32 + (size_t)(t * 16 + srow * 4) * CCH + col;    \
            XN0 = xp_[0 * CCH]; XN1 = xp_[1 * CCH];                            \
            XN2 = xp_[2 * CCH]; XN3 = xp_[3 * CCH];                            \
        }                                                                      \
        const int nbp_ = (t - stride) * 16;                                    \
        GATHER_A(AN, (PUB_ON ? ((P) ^ 1) : 0), (t + stride < ntiles ? (t + stride) * 16 : (ntiles - 1) * 16)) \
        __builtin_amdgcn_sched_barrier(0);                                     \
        v4i acc0 = {0,0,0,0}, acc1 = {0,0,0,0}, acc2 = {0,0,0,0}, acc3 = {0,0,0,0}; \
        if (MFMA_ON) {                                                         \
            __builtin_amdgcn_s_setprio(1);                                     \
            _Pragma("unroll")                                                  \
            for (int j = 0; j < 7; ++j) {                                      \
                acc0 = __builtin_amdgcn_mfma_i32_16x16x64_i8(AC[j], wreg[j][0], acc0, 0, 0, 0); \
                acc1 = __builtin_amdgcn_mfma_i32_16x16x64_i8(AC[j], wreg[j][1], acc1, 0, 0, 0); \
                acc2 = __builtin_amdgcn_mfma_i32_16x16x64_i8(AC[j], wreg[j][2], acc2, 0, 0, 0); \
                acc3 = __builtin_amdgcn_mfma_i32_16x16x64_i8(AC[j], wreg[j][3], acc3, 0, 0, 0); \
            }                                                                  \
            __builtin_amdgcn_s_setprio(0);                                     \
        } else {                                                               \
            _Pragma("unroll")                                                  \
            for (int j = 0; j < 7; ++j)                                        \
                asm volatile("" :: "v"(AC[j][0]), "v"(AC[j][1]),               \
                                   "v"(AC[j][2]), "v"(AC[j][3]));              \
        }                                                                      \
        if (STORE_ON) {                                                        \
            if (wv != 0) s_red[P][wv][0][lane] = acc0;                         \
            if (wv != 1) s_red[P][wv][1][lane] = acc1;                         \
            if (wv != 2) s_red[P][wv][2][lane] = acc2;                         \
            if (wv != 3) s_red[P][wv][3][lane] = acc3;                         \
            if (DO_EPI) {                                                      \
                v4i tot = accP;                                                \
                _Pragma("unroll")                                              \
                for (int w = 0; w < 4; ++w) {                                  \
                    if (w != wv) {                                             \
                        const v4i r_ = s_red[(P) ^ 1][w][wv][lane];            \
                        tot[0] += r_[0]; tot[1] += r_[1];                      \
                        tot[2] += r_[2]; tot[3] += r_[3];                      \
                    }                                                          \
                }                                                              \
                EPILOGUE(tot, nbp_, XC0, XC1, XC2, XC3)                        \
            }                                                                  \
            accP = (wv == 0) ? acc0 : (wv == 1) ? acc1 : (wv == 2) ? acc2 : acc3; \
        } else {                                                               \
            asm volatile("" :: "v"(acc0[0]), "v"(acc1[0]),                     \
                               "v"(acc2[0]), "v"(acc3[0]));                    \
        }                                                                      \
        if (PUB_ON) {                                                          \
            offl[(P) * OFFSTR + slot0] = (PFCm0 ? PFCa0 : nvox) << 6;          \
            offl[(P) * OFFSTR + slot1] = (PFCm1 ? PFCa1 : nvox) << 6;          \
        }                                                                      \
        if (BAR_ON) {                                                          \
            asm volatile("s_waitcnt lgkmcnt(0)" ::: "memory");                 \
            __builtin_amdgcn_s_barrier();                                      \
        } else {                                                               \
            __builtin_amdgcn_sched_barrier(0);                                 \
        }                                                                      \
    } while (0)

    for (int rep = 0; rep < REP; ++rep) {
        v4i aA[7], aB[7];
        v4i accP = {0, 0, 0, 0};
        int pAa0 = 0, pAm0 = 0, pAa1 = 0, pAm1 = 0;
        int pBa0 = 0, pBm0 = 0, pBa1 = 0, pBm1 = 0;
        int xA0 = 0, xA1 = 0, xA2 = 0, xA3 = 0, xB0 = 0, xB1 = 0, xB2 = 0, xB3 = 0;

        __syncthreads();   // protect s_off across reps
        {
            const size_t base = (size_t)t0 * (16 * KK);
            const int a0 = in_idx[base + e0], m0 = mask[base + e0];
            const int a1 = in_idx[base + e1], m1 = mask[base + e1];
            offl[0 * OFFSTR + slot0] = (m0 ? a0 : nvox) << 6;
            offl[0 * OFFSTR + slot1] = (m1 ? a1 : nvox) << 6;
        }
        int pa0 = 0, pa1 = 0, pm0 = 0, pm1 = 0;
        if (PUB_ON) {
            int t1c = t0 + stride; if (t1c >= ntiles) t1c = ntiles - 1;
            const size_t base = (size_t)t1c * (16 * KK);
            pa0 = in_idx[base + e0]; pm0 = mask[base + e0];
            pa1 = in_idx[base + e1]; pm1 = mask[base + e1];
            int t2c = t0 + 2 * stride; if (t2c >= ntiles) t2c = ntiles - 1;
            const size_t base2 = (size_t)t2c * (16 * KK);
            pAa0 = in_idx[base2 + e0]; pAm0 = mask[base2 + e0];
            pAa1 = in_idx[base2 + e1]; pAm1 = mask[base2 + e1];
        }
        __syncthreads();
        GATHER_A(aA, 0, t0 * 16)
        if (PUB_ON) {
            offl[1 * OFFSTR + slot0] = (pm0 ? pa0 : nvox) << 6;
            offl[1 * OFFSTR + slot1] = (pm1 ? pa1 : nvox) << 6;
        }
        asm volatile("s_waitcnt lgkmcnt(0)" ::: "memory");
        __builtin_amdgcn_s_barrier();

        int t = t0;
        ITER(aA, aB, 0, 0, pAa0, pAm0, pAa1, pAm1, pBa0, pBm0, pBa1, pBm1,
             xA0, xA1, xA2, xA3, xB0, xB1, xB2, xB3);
        t += stride;
        int i = 1;
        while (i < cnt) {
            ITER(aB, aA, 1, 1, pBa0, pBm0, pBa1, pBm1, pAa0, pAm0, pAa1, pAm1,
                 xB0, xB1, xB2, xB3, xA0, xA1, xA2, xA3);
            ++i; t += stride; if (i >= cnt) break;
            ITER(aA, aB, 0, 1, pAa0, pAm0, pAa1, pAm1, pBa0, pBm0, pBa1, pBm1,
                 xA0, xA1, xA2, xA3, xB0, xB1, xB2, xB3);
            ++i; t += stride;
        }

        {
            const int pl = (cnt - 1) & 1;
            const int nbl = (t0 + (cnt - 1) * stride) * 16;
            if (STORE_ON) {
                int x0 = 0, x1 = 0, x2 = 0, x3 = 0;
                if (LAYER == 2) {
                    const int* xp_ = x32 + (size_t)(nbl + srow * 4) * CCH + col;
                    x0 = xp_[0 * CCH]; x1 = xp_[1 * CCH];
                    x2 = xp_[2 * CCH]; x3 = xp_[3 * CCH];
                }
                v4i tot = accP;
#pragma unroll
                for (int w = 0; w < 4; ++w) {
                    if (w != wv) {
                        const v4i r_ = s_red[pl][w][wv][lane];
                        tot[0] += r_[0]; tot[1] += r_[1];
                        tot[2] += r_[2]; tot[3] += r_[3];
                    }
                }
                EPILOGUE(tot, nbl, x0, x1, x2, x3)
            } else {
                asm volatile("" :: "v"(accP[0]));
            }
        }
    }
#undef ITER
#undef EPILOGUE
#undef GATHER_A
}

extern "C" void kernel_launch(void* const* d_in, const int* in_sizes, int n_in,
                              void* d_out, int out_size, void* d_ws, size_t ws_size,
                              hipStream_t stream) {
    const int* x32    = (const int*)d_in[0];
    const int* in_idx = (const int*)d_in[1];
    const int* mask   = (const int*)d_in[2];
    const int* w1_32  = (const int*)d_in[3];
    const int* b1     = (const int*)d_in[4];
    const int* comp1  = (const int*)d_in[5];
    const int* w2_32  = (const int*)d_in[6];
    const int* b2     = (const int*)d_in[7];
    const int* comp2  = (const int*)d_in[8];
    const int* mul0   = (const int*)d_in[9];
    const int* mul1   = (const int*)d_in[10];
    const int* slope  = (const int*)d_in[11];

    const int nvox = in_sizes[0] / CCH;
    const size_t wext_b = (size_t)28 * CCH * CCH;
    const size_t fbytes = (size_t)(nvox + 1) * CCH;
    const size_t falign = (fbytes + 255) & ~(size_t)255;
    const size_t walign = (wext_b + 255) & ~(size_t)255;

    int8_t* q0;
    int8_t* q1;
    int8_t* w1e;
    int8_t* w2e;
    int8_t* af;
    bool ws_main = ws_size >= 3 * falign + 2 * walign;
    if (ws_main) {
        q0  = (int8_t*)d_ws;
        q1  = q0 + falign;
        w1e = q1 + falign;
        w2e = w1e + walign;
        af  = w2e + walign;
    } else {
        q0  = (int8_t*)d_out;
        q1  = (int8_t*)d_ws;
        w1e = q1 + falign;
        w2e = w1e + walign;
        af  = w2e + walign;
    }

    const int total4 = (nvox * CCH) / 4;
    const int pb1 = (2 * WN + 8192 + 32 + 255) / 256;
    const int af_blocks  = (nvox + 255) / 256;
    const int req_blocks = (total4 + 255) / 256;
    k_prep<<<pb1 + af_blocks + req_blocks, 256, 0, stream>>>(
        x32, mul0, w1_32, w2_32, comp1, b1, comp2, b2, mask,
        w1e, w2e, (int*)q0, (int*)q1, af, pb1, af_blocks, nvox, total4);

    const int ntiles = nvox / 16;
    int cblocks = 512;
    if (cblocks > ntiles) cblocks = ntiles;
    k_conv<1, 0, 1><<<cblocks, 256, 0, stream>>>(q0, in_idx, mask, w1e, af,
                                                 mul1, slope, nullptr,
                                                 q1, nullptr, nvox, ntiles);
    k_conv<2, 0, 1><<<cblocks, 256, 0, stream>>>(q1, in_idx, mask, w2e, af,
                                                 nullptr, nullptr, x32,
                                                 nullptr, (int*)d_out, nvox, ntiles);

    // ---- diagnostic ablations (scratch output; only if workspace has room) ----
    if (ws_main && ws_size >= 4 * falign + 2 * walign) {
        int8_t* ablout = af + falign;   // dead scratch, rewritten by prep next call
        k_conv<1, 0, 4><<<cblocks, 256, 0, stream>>>(q0, in_idx, mask, w1e, af,
                                                     mul1, slope, nullptr,
                                                     ablout, nullptr, nvox, ntiles);
        k_conv<1, 1, 4><<<cblocks, 256, 0, stream>>>(q0, in_idx, mask, w1e, af,
                                                     mul1, slope, nullptr,
                                                     ablout, nullptr, nvox, ntiles);
        k_conv<1, 2, 4><<<cblocks, 256, 0, stream>>>(q0, in_idx, mask, w1e, af,
                                                     mul1, slope, nullptr,
                                                     ablout, nullptr, nvox, ntiles);
        k_conv<1, 3, 4><<<cblocks, 256, 0, stream>>>(q0, in_idx, mask, w1e, af,
                                                     mul1, slope, nullptr,
                                                     ablout, nullptr, nvox, ntiles);
        k_conv<1, 4, 4><<<cblocks, 256, 0, stream>>>(q0, in_idx, mask, w1e, af,
                                                     mul1, slope, nullptr,
                                                     ablout, nullptr, nvox, ntiles);
        k_conv<1, 5, 4><<<cblocks, 256, 0, stream>>>(q0, in_idx, mask, w1e, af,
                                                     mul1, slope, nullptr,
                                                     ablout, nullptr, nvox, ntiles);
    }
}

// Round 16
// 63.405 us; speedup vs baseline: 5.5720x; 5.5720x over previous
//
#include <hip/hip_runtime.h>
#include <stdint.h>

#define CCH 64
#define KK 27
#define WN (KK * CCH * CCH)   // 110592

typedef int v4i __attribute__((ext_vector_type(4)));

// ---------------- prep: weights + affine slice + af rows + requant + zero rows ----
// exact: (x*mul)>>31 == mulhi(x, mul<<1); (x*slope)>>25 == mulhi(x, slope<<7)
__global__ void __launch_bounds__(256) k_prep(
    const int* __restrict__ x32, const int* __restrict__ mul0p,
    const int* __restrict__ w1_32, const int* __restrict__ w2_32,
    const int* __restrict__ comp1, const int* __restrict__ b1,
    const int* __restrict__ comp2, const int* __restrict__ b2,
    const int* __restrict__ mask,
    int8_t* __restrict__ w1e, int8_t* __restrict__ w2e,
    int* __restrict__ q0, int* __restrict__ q1, int8_t* __restrict__ af,
    int pb1, int af_blocks, int nvox, int total4)
{
    const int bid = blockIdx.x;
    if (bid < pb1) {
        const int gtid = bid * 256 + threadIdx.x;
        if (gtid < WN) {
            w1e[gtid] = (int8_t)w1_32[gtid];
        } else if (gtid < 2 * WN) {
            w2e[gtid - WN] = (int8_t)w2_32[gtid - WN];
        } else if (gtid < 2 * WN + 8192) {
            int u = gtid - 2 * WN;
            const int which = u >> 12;
            u &= 4095;
            const int col = u >> 6, j = u & 63;
            const int* comp = which ? comp2 : comp1;
            const int* bias = which ? b2 : b1;
            int v;
            if (j < 27)       v = comp[j * CCH + col] >> 2;       // pairs A=4*mask
            else if (j < 54)  v = comp[(j - 27) * CCH + col] & 3; // pairs A=1*mask
            else if (j == 54) v = bias[col] >> 6;                 // pairs A=64
            else if (j == 55) v = bias[col] & 63;                 // pairs A=1
            else              v = 0;
            (which ? w2e : w1e)[27 * 4096 + col * 64 + j] = (int8_t)v;
        } else {
            const int u = gtid - 2 * WN - 8192;   // zero rows (row nvox of q0,q1)
            if (u < 16)       q0[(size_t)nvox * 16 + u] = 0;
            else if (u < 32)  q1[(size_t)nvox * 16 + (u - 16)] = 0;
        }
    } else if (bid < pb1 + af_blocks) {
        // affine A-rows: af[vox][j] = j<27?4m : j<54?m : j==54?64 : j==55?1 : 0
        const int vox = (bid - pb1) * 256 + threadIdx.x;
        if (vox < nvox) {
            int m[27];
#pragma unroll
            for (int k = 0; k < 27; ++k)
                m[k] = mask[(size_t)vox * 27 + k] ? 1 : 0;
            v4i d0, d1, d2, d3;
#pragma unroll
            for (int di = 0; di < 16; ++di) {
                int pk = 0;
#pragma unroll
                for (int b = 0; b < 4; ++b) {
                    const int ch = di * 4 + b;
                    int bv = 0;
                    if (ch < 27)       bv = m[ch] << 2;
                    else if (ch < 54)  bv = m[ch - 27];
                    else if (ch == 54) bv = 64;
                    else if (ch == 55) bv = 1;
                    pk |= bv << (8 * b);
                }
                if (di < 4)       d0[di] = pk;
                else if (di < 8)  d1[di - 4] = pk;
                else if (di < 12) d2[di - 8] = pk;
                else              d3[di - 12] = pk;
            }
            v4i* dst = (v4i*)(af + (size_t)vox * 64);
            dst[0] = d0; dst[1] = d1; dst[2] = d2; dst[3] = d3;
        }
    } else {
        const int i = (bid - pb1 - af_blocks) * 256 + threadIdx.x;
        if (i < total4) {
            const int mul2 = (*mul0p) << 1;
            const int4 v = ((const int4*)x32)[i];
            int r = 0, q;
            q = __mulhi(v.x, mul2); q = q > 127 ? 127 : (q < -127 ? -127 : q); r |= (q & 0xff);
            q = __mulhi(v.y, mul2); q = q > 127 ? 127 : (q < -127 ? -127 : q); r |= (q & 0xff) << 8;
            q = __mulhi(v.z, mul2); q = q > 127 ? 127 : (q < -127 ? -127 : q); r |= (q & 0xff) << 16;
            q = __mulhi(v.w, mul2); q = q > 127 ? 127 : (q < -127 ? -127 : q); r |= (q & 0xff) << 24;
            q0[i] = r;
        }
    }
}

// k-split MFMA conv (r14 structure), grid raised to 4 blocks/CU.
// Ablation (r15) showed: gather-path ~5us + mfma-path ~5us serialize per wave
// while barrier/stores/idx-stream are free -> more resident blocks per CU is
// the overlap lever. VGPR=116 (4 waves/SIMD fits), LDS=37.4KB (4 blocks/CU fits).
// REQUIRES nvox % 16 == 0 (100000 = 6250*16).
template <int LAYER>
__global__ void __launch_bounds__(256, 2)
k_conv(const int8_t* __restrict__ fin,   // [(nvox+1)*64] int8 (row nvox = zeros)
       const int* __restrict__ in_idx,   // [nvox*27]
       const int* __restrict__ mask,     // [nvox*27] (0/1)
       const int8_t* __restrict__ wext,  // [28*64*64] packed int8
       const int8_t* __restrict__ af,    // [nvox*64] affine A-rows
       const int* __restrict__ mul1,     // [64]   (layer 1)
       const int* __restrict__ slopep,   // scalar (layer 1)
       const int* __restrict__ x32,      // [nvox*64] residual (layer 2)
       int8_t* __restrict__ q1out,       // layer-1 output
       int* __restrict__ out,            // layer-2 output
       int nvox, int ntiles)
{
    __shared__ int s_off[2][16][36];          // [slot][row][wv*8+j] byte offsets
    __shared__ v4i s_red[2][4][4][64];        // [parity][writer][group][lane]

    const int tid  = threadIdx.x;
    const int lane = tid & 63;
    const int wv   = tid >> 6;
    const int arow = lane & 15;
    const int srow = lane >> 4;
    const int col  = wv * 16 + arow;

    const int e0 = tid;            // 0..255
    const int e1 = tid + 176;      // 176..431 (dup writes benign: same values)
    const int r0 = e0 / 27, s0 = e0 - r0 * 27;
    const int r1 = e1 / 27, s1 = e1 - r1 * 27;
    const int slot0 = r0 * 36 + (s0 / 7) * 8 + (s0 % 7);
    const int slot1 = r1 * 36 + (s1 / 7) * 8 + (s1 % 7);
    int* const offl = &s_off[0][0][0];
    const int OFFSTR = 16 * 36;

    v4i wreg[7][4];
#pragma unroll
    for (int j = 0; j < 7; ++j)
#pragma unroll
        for (int g = 0; g < 4; ++g)
            wreg[j][g] = *(const v4i*)(wext +
                ((size_t)((7 * wv + j) * CCH + g * 16 + arow)) * CCH + srow * 16);

    const int mul2     = (LAYER == 1) ? (mul1[col] << 1) : 0;
    const int slope128 = (LAYER == 1) ? ((*slopep) << 7) : 0;

    const int stride = gridDim.x;
    const int t0 = blockIdx.x;
    if (t0 >= ntiles) return;
    const int cnt = (ntiles - 1 - t0) / stride + 1;

    v4i aA[7], aB[7];
    v4i accP = {0, 0, 0, 0};
    int pAa0, pAm0, pAa1, pAm1, pBa0, pBm0, pBa1, pBm1;
    int xA0 = 0, xA1 = 0, xA2 = 0, xA3 = 0, xB0 = 0, xB1 = 0, xB2 = 0, xB3 = 0;

#define GATHER_A(AN, SN, NB)                                                   \
    {                                                                          \
        const v4i o0_ = *(const v4i*)&s_off[SN][arow][wv * 8];                 \
        const v4i o1_ = *(const v4i*)&s_off[SN][arow][wv * 8 + 4];             \
        const int offs_[7] = {o0_[0], o0_[1], o0_[2], o0_[3],                  \
                              o1_[0], o1_[1], o1_[2]};                         \
        _Pragma("unroll")                                                      \
        for (int j = 0; j < 7; ++j) {                                          \
            if (wv == 3 && j == 6) {                                           \
                AN[6] = *(const v4i*)(af + (size_t)((NB) + arow) * CCH + srow * 16); \
            } else {                                                           \
                AN[j] = *(const v4i*)(fin + offs_[j] + srow * 16);             \
            }                                                                  \
        }                                                                      \
    }

#define EPILOGUE(TOT, NBP, X0, X1, X2, X3)                                     \
    if (LAYER == 1) {                                                          \
        int8_t* rp_ = q1out + (size_t)((NBP) + srow * 4) * CCH + col;          \
        _Pragma("unroll")                                                      \
        for (int r = 0; r < 4; ++r) {                                          \
            const int v_ = TOT[r];                                             \
            const int p_ = (v_ >= 0) ? v_ : __mulhi(v_, slope128);             \
            int q_ = __mulhi(p_, mul2);                                        \
            q_ = q_ > 127 ? 127 : (q_ < -127 ? -127 : q_);                     \
            rp_[r * CCH] = (int8_t)q_;                                         \
        }                                                                      \
    } else {                                                                   \
        int* rp_ = out + (size_t)((NBP) + srow * 4) * CCH + col;               \
        rp_[0 * CCH] = TOT[0] + X0;                                            \
        rp_[1 * CCH] = TOT[1] + X1;                                            \
        rp_[2 * CCH] = TOT[2] + X2;                                            \
        rp_[3 * CCH] = TOT[3] + X3;                                            \
    }

#define ITER(AC, AN, P, DO_EPI, PFCa0, PFCm0, PFCa1, PFCm1,                    \
             PFNa0, PFNm0, PFNa1, PFNm1, XC0, XC1, XC2, XC3, XN0, XN1, XN2, XN3) \
    do {                                                                       \
        int tp3_ = t + 3 * stride; if (tp3_ >= ntiles) tp3_ = ntiles - 1;      \
        const size_t b3_ = (size_t)tp3_ * (16 * KK);                           \
        PFNa0 = in_idx[b3_ + e0]; PFNm0 = mask[b3_ + e0];                      \
        PFNa1 = in_idx[b3_ + e1]; PFNm1 = mask[b3_ + e1];                      \
        if (LAYER == 2) {                                                      \
            const int* xp_ = x32 + (size_t)(t * 16 + srow * 4) * CCH + col;    \
            XN0 = xp_[0 * CCH]; XN1 = xp_[1 * CCH];                            \
            XN2 = xp_[2 * CCH]; XN3 = xp_[3 * CCH];                            \
        }                                                                      \
        const int nbp_ = (t - stride) * 16;                                    \
        GATHER_A(AN, (P) ^ 1, (t + stride < ntiles ? (t + stride) * 16 : (ntiles - 1) * 16)) \
        __builtin_amdgcn_sched_barrier(0);                                     \
        v4i acc0 = {0,0,0,0}, acc1 = {0,0,0,0}, acc2 = {0,0,0,0}, acc3 = {0,0,0,0}; \
        __builtin_amdgcn_s_setprio(1);                                         \
        _Pragma("unroll")                                                      \
        for (int j = 0; j < 7; ++j) {                                          \
            acc0 = __builtin_amdgcn_mfma_i32_16x16x64_i8(AC[j], wreg[j][0], acc0, 0, 0, 0); \
            acc1 = __builtin_amdgcn_mfma_i32_16x16x64_i8(AC[j], wreg[j][1], acc1, 0, 0, 0); \
            acc2 = __builtin_amdgcn_mfma_i32_16x16x64_i8(AC[j], wreg[j][2], acc2, 0, 0, 0); \
            acc3 = __builtin_amdgcn_mfma_i32_16x16x64_i8(AC[j], wreg[j][3], acc3, 0, 0, 0); \
        }                                                                      \
        __builtin_amdgcn_s_setprio(0);                                         \
        if (wv != 0) s_red[P][wv][0][lane] = acc0;                             \
        if (wv != 1) s_red[P][wv][1][lane] = acc1;                             \
        if (wv != 2) s_red[P][wv][2][lane] = acc2;                             \
        if (wv != 3) s_red[P][wv][3][lane] = acc3;                             \
        if (DO_EPI) {                                                          \
            v4i tot = accP;                                                    \
            _Pragma("unroll")                                                  \
            for (int w = 0; w < 4; ++w) {                                      \
                if (w != wv) {                                                 \
                    const v4i r_ = s_red[(P) ^ 1][w][wv][lane];                \
                    tot[0] += r_[0]; tot[1] += r_[1];                          \
                    tot[2] += r_[2]; tot[3] += r_[3];                          \
                }                                                              \
            }                                                                  \
            EPILOGUE(tot, nbp_, XC0, XC1, XC2, XC3)                            \
        }                                                                      \
        offl[(P) * OFFSTR + slot0] = (PFCm0 ? PFCa0 : nvox) << 6;              \
        offl[(P) * OFFSTR + slot1] = (PFCm1 ? PFCa1 : nvox) << 6;              \
        accP = (wv == 0) ? acc0 : (wv == 1) ? acc1 : (wv == 2) ? acc2 : acc3;  \
        asm volatile("s_waitcnt lgkmcnt(0)" ::: "memory");                     \
        __builtin_amdgcn_s_barrier();                                          \
    } while (0)

    // ---- prologue ----
    {
        const size_t base = (size_t)t0 * (16 * KK);
        const int a0 = in_idx[base + e0], m0 = mask[base + e0];
        const int a1 = in_idx[base + e1], m1 = mask[base + e1];
        offl[0 * OFFSTR + slot0] = (m0 ? a0 : nvox) << 6;
        offl[0 * OFFSTR + slot1] = (m1 ? a1 : nvox) << 6;
    }
    int pa0, pa1, pm0, pm1;
    {
        int t1c = t0 + stride; if (t1c >= ntiles) t1c = ntiles - 1;
        const size_t base = (size_t)t1c * (16 * KK);
        pa0 = in_idx[base + e0]; pm0 = mask[base + e0];
        pa1 = in_idx[base + e1]; pm1 = mask[base + e1];
    }
    {
        int t2c = t0 + 2 * stride; if (t2c >= ntiles) t2c = ntiles - 1;
        const size_t base = (size_t)t2c * (16 * KK);
        pAa0 = in_idx[base + e0]; pAm0 = mask[base + e0];
        pAa1 = in_idx[base + e1]; pAm1 = mask[base + e1];
    }
    __syncthreads();
    GATHER_A(aA, 0, t0 * 16)
    offl[1 * OFFSTR + slot0] = (pm0 ? pa0 : nvox) << 6;
    offl[1 * OFFSTR + slot1] = (pm1 ? pa1 : nvox) << 6;
    asm volatile("s_waitcnt lgkmcnt(0)" ::: "memory");
    __builtin_amdgcn_s_barrier();

    // ---- main loop (2x unrolled: A-buf, PF pair, X pair all swap) ----
    int t = t0;
    ITER(aA, aB, 0, 0, pAa0, pAm0, pAa1, pAm1, pBa0, pBm0, pBa1, pBm1,
         xA0, xA1, xA2, xA3, xB0, xB1, xB2, xB3);
    t += stride;
    int i = 1;
    while (i < cnt) {
        ITER(aB, aA, 1, 1, pBa0, pBm0, pBa1, pBm1, pAa0, pAm0, pAa1, pAm1,
             xB0, xB1, xB2, xB3, xA0, xA1, xA2, xA3);
        ++i; t += stride; if (i >= cnt) break;
        ITER(aA, aB, 0, 1, pAa0, pAm0, pAa1, pAm1, pBa0, pBm0, pBa1, pBm1,
             xA0, xA1, xA2, xA3, xB0, xB1, xB2, xB3);
        ++i; t += stride;
    }

    // ---- drain ----
    {
        const int pl = (cnt - 1) & 1;
        const int nbl = (t0 + (cnt - 1) * stride) * 16;
        int x0 = 0, x1 = 0, x2 = 0, x3 = 0;
        if (LAYER == 2) {
            const int* xp_ = x32 + (size_t)(nbl + srow * 4) * CCH + col;
            x0 = xp_[0 * CCH]; x1 = xp_[1 * CCH];
            x2 = xp_[2 * CCH]; x3 = xp_[3 * CCH];
        }
        v4i tot = accP;
#pragma unroll
        for (int w = 0; w < 4; ++w) {
            if (w != wv) {
                const v4i r_ = s_red[pl][w][wv][lane];
                tot[0] += r_[0]; tot[1] += r_[1];
                tot[2] += r_[2]; tot[3] += r_[3];
            }
        }
        EPILOGUE(tot, nbl, x0, x1, x2, x3)
    }
#undef ITER
#undef EPILOGUE
#undef GATHER_A
}

extern "C" void kernel_launch(void* const* d_in, const int* in_sizes, int n_in,
                              void* d_out, int out_size, void* d_ws, size_t ws_size,
                              hipStream_t stream) {
    // ALL integer inputs arrive as int32 on device, regardless of reference dtype.
    const int* x32    = (const int*)d_in[0];
    const int* in_idx = (const int*)d_in[1];
    const int* mask   = (const int*)d_in[2];
    const int* w1_32  = (const int*)d_in[3];
    const int* b1     = (const int*)d_in[4];
    const int* comp1  = (const int*)d_in[5];
    const int* w2_32  = (const int*)d_in[6];
    const int* b2     = (const int*)d_in[7];
    const int* comp2  = (const int*)d_in[8];
    const int* mul0   = (const int*)d_in[9];
    const int* mul1   = (const int*)d_in[10];
    const int* slope  = (const int*)d_in[11];

    const int nvox = in_sizes[0] / CCH;                 // 100000 (%16==0)
    const size_t wext_b = (size_t)28 * CCH * CCH;       // 114688 per layer
    const size_t fbytes = (size_t)(nvox + 1) * CCH;     // +1 zero row
    const size_t falign = (fbytes + 255) & ~(size_t)255;
    const size_t walign = (wext_b + 255) & ~(size_t)255;

    int8_t* q0;
    int8_t* q1;
    int8_t* w1e;
    int8_t* w2e;
    int8_t* af;
    if (ws_size >= 3 * falign + 2 * walign) {
        q0  = (int8_t*)d_ws;
        q1  = q0 + falign;
        w1e = q1 + falign;
        w2e = w1e + walign;
        af  = w2e + walign;
    } else {
        // stage q0 in d_out's bytes (dead after conv1; conv2 rewrites d_out fully)
        q0  = (int8_t*)d_out;
        q1  = (int8_t*)d_ws;
        w1e = q1 + falign;
        w2e = w1e + walign;
        af  = w2e + walign;
    }

    const int total4 = (nvox * CCH) / 4;                          // 1.6e6
    const int pb1 = (2 * WN + 8192 + 32 + 255) / 256;             // 897
    const int af_blocks  = (nvox + 255) / 256;                    // 391
    const int req_blocks = (total4 + 255) / 256;                  // 6250
    k_prep<<<pb1 + af_blocks + req_blocks, 256, 0, stream>>>(
        x32, mul0, w1_32, w2_32, comp1, b1, comp2, b2, mask,
        w1e, w2e, (int*)q0, (int*)q1, af, pb1, af_blocks, nvox, total4);

    const int ntiles = nvox / 16;                       // 6250 (exact)
    int cblocks = 1024;                                 // 4 resident blocks/CU
    if (cblocks > ntiles) cblocks = ntiles;
    k_conv<1><<<cblocks, 256, 0, stream>>>(q0, in_idx, mask, w1e, af,
                                           mul1, slope, nullptr,
                                           q1, nullptr, nvox, ntiles);
    k_conv<2><<<cblocks, 256, 0, stream>>>(q1, in_idx, mask, w2e, af,
                                           nullptr, nullptr, x32,
                                           nullptr, (int*)d_out, nvox, ntiles);
}